// Round 1
// baseline (363.801 us; speedup 1.0000x reference)
//
#include <hip/hip_runtime.h>

// LinkPredictor: score[e] = w2 . relu(W1 . concat(h[src[e]], h[dst[e]]) + b1) + b2
// N_NODES=100000, N_EDGES=1600000, D=128, HIDDEN=256
//
// R13: edge_score rewritten for occupancy + MLP.
//   Old: 16-lane groups x 4 edges, 16B/lane, w2v[16] -> 68 VGPR (over the
//   64-VGPR cliff, 16 waves/CU cap, measured occ 29%, 3.56 TB/s, latency-bound).
//   New: one wave owns 4 edges at 8B/lane (lane l holds hidden dims 4l..4l+3):
//   - each 512B U row = ONE global_load_dwordx2 (single segment per instr)
//   - w2v[4] instead of w2v[16]; indices via readfirstlane -> SGPR saddr loads
//   - 6-level wave butterfly reduction; lane 0 stores float4 per group
//   Target ~44 VGPR -> 32 waves/CU; predict hbm_gbps 3.56 -> >=5 TB/s.

#define NNODES 100000
#define E_TOTAL 1600000
#define D 128
#define K2 256
#define H 256

typedef short bf16x8 __attribute__((ext_vector_type(8)));
typedef short bf16x4 __attribute__((ext_vector_type(4)));
typedef float f32x4 __attribute__((ext_vector_type(4)));
typedef const __attribute__((address_space(1))) unsigned short* gas_t;
typedef __attribute__((address_space(3))) unsigned short* las_t;

__device__ __forceinline__ unsigned short f2bf(float f) {
    unsigned u = __float_as_uint(f);
    u += 0x7fff + ((u >> 16) & 1);   // round-to-nearest-even
    return (unsigned short)(u >> 16);
}
__device__ __forceinline__ float bf2f(unsigned short s) {
    return __uint_as_float((unsigned)s << 16);
}

// ---------------- cvt: h and W1 -> bf16 ----------------
__global__ void cvt_kernel(const float* __restrict__ h, const float* __restrict__ w1,
                           unsigned short* __restrict__ hbf, unsigned short* __restrict__ w1bf,
                           int n4h, int n4w) {
    int i = blockIdx.x * blockDim.x + threadIdx.x;
    const float* s; unsigned short* d; int j;
    if (i < n4h) { s = h; d = hbf; j = i; }
    else if (i < n4h + n4w) { s = w1; d = w1bf; j = i - n4h; }
    else return;
    float4 v = ((const float4*)s)[j];
    ushort4 o;
    o.x = f2bf(v.x); o.y = f2bf(v.y); o.z = f2bf(v.z); o.w = f2bf(v.w);
    ((ushort4*)d)[j] = o;
}

// ---------------- u_gemm v3: N-split, direct C-layout stores ----------------
// blockIdx bx: tile = bx>>2 (64 node rows), half = (bx>>1)&1 (0: Us + b1 fold,
// 1: Ud), nh = bx&1 (cols 0-127 vs 128-255 of the half's output).
// Wave w owns true cols n = nh*128 + w*32 + nt*16 + l15, nt in {0,1}.
// Store: row m, lane l15 packs (nt0,nt1) -> dword at short-offset
// nh*128 + w*32 + l15*2  (c' = that + nt).
__global__ __launch_bounds__(256, 4) void u_gemm3(
    const unsigned short* __restrict__ hbf,
    const unsigned short* __restrict__ w1bf,
    const float* __restrict__ b1,
    unsigned short* __restrict__ Us,
    unsigned short* __restrict__ Ud)
{
    __shared__ __align__(16) unsigned short A[64 * 128];   // 16384 B

    const int tid = threadIdx.x;
    const int wave = tid >> 6;
    const int lane = tid & 63;
    const int l15 = lane & 15;
    const int quad = lane >> 4;

    const int tile = blockIdx.x >> 2;
    const int half = (blockIdx.x >> 1) & 1;
    const int nh = blockIdx.x & 1;
    const int r0 = tile * 64;
    int rows = NNODES - r0; if (rows > 64) rows = 64;
    const int koff = half * 128;
    unsigned short* U = half ? Ud : Us;

    // --- issue async stage of A (16 KB), XOR swizzle c = p ^ (r&15) ---
#pragma unroll
    for (int it = 0; it < 4; ++it) {
        const int s = it * 256 + tid;      // 16B slot 0..1023
        const int r = s >> 4;              // row 0..63
        const int p = s & 15;              // position chunk
        const int c = p ^ (r & 15);        // content chunk
        if (r < rows)
            __builtin_amdgcn_global_load_lds(
                (gas_t)(hbf + (size_t)(r0 + r) * D + c * 8),
                (las_t)(A + it * 2048 + wave * 512), 16, 0, 0);
    }

    // --- B fragments + bias while DMA is in flight ---
    bf16x8 B[4][2];
    float bias[2];
#pragma unroll
    for (int nt = 0; nt < 2; ++nt) {
        const int n = nh * 128 + wave * 32 + nt * 16 + l15;
        bias[nt] = half ? 0.f : b1[n];
#pragma unroll
        for (int kit = 0; kit < 4; ++kit)
            B[kit][nt] = *(const bf16x8*)(w1bf + (size_t)n * K2 + koff + kit * 32 + quad * 8);
    }

    __syncthreads();   // vmcnt(0): A landed

    f32x4 acc[4][2];
    const f32x4 zero = {0.f, 0.f, 0.f, 0.f};
#pragma unroll
    for (int ms = 0; ms < 4; ++ms)
#pragma unroll
        for (int nt = 0; nt < 2; ++nt)
            acc[ms][nt] = zero;

#pragma unroll
    for (int kit = 0; kit < 4; ++kit) {
        bf16x8 a[4];
#pragma unroll
        for (int ms = 0; ms < 4; ++ms) {
            const int row = ms * 16 + l15;
            const int p = (kit * 4 + quad) ^ l15;
            a[ms] = *(const bf16x8*)&A[row * 128 + p * 8];
        }
#pragma unroll
        for (int ms = 0; ms < 4; ++ms)
#pragma unroll
            for (int nt = 0; nt < 2; ++nt)
                acc[ms][nt] = __builtin_amdgcn_mfma_f32_16x16x32_bf16(
                    a[ms], B[kit][nt], acc[ms][nt], 0, 0, 0);
    }

    // --- direct permuted store: dword per (ms,r), 64B segment per quad ---
    const int coff = nh * 128 + wave * 32 + l15 * 2;   // short offset in U row
#pragma unroll
    for (int ms = 0; ms < 4; ++ms) {
#pragma unroll
        for (int r = 0; r < 4; ++r) {
            const int m = ms * 16 + quad * 4 + r;
            if (m < rows) {
                const unsigned lo = f2bf(acc[ms][0][r] + bias[0]);
                const unsigned hi = f2bf(acc[ms][1][r] + bias[1]);
                *(unsigned*)(U + (size_t)(r0 + m) * H + coff) = lo | (hi << 16);
            }
        }
    }
}

// ---------------- edge pass (R13: wave-per-4-edges, 8B/lane) ----------------
// U' layout: within each 32-col block, c'' = l15*2+nt holds n'' = nt*16+l15.
// Lane l covers short offsets cp in [4l, 4l+4); w2v[jj] = w2[n(4l+jj)].
// One wave owns 4 consecutive edges: each U row is a single dwordx2 wave load.
__global__ __launch_bounds__(256) void edge_score(
    const unsigned short* __restrict__ Us,
    const unsigned short* __restrict__ Ud,
    const int* __restrict__ srcE,
    const int* __restrict__ dstE,
    const float* __restrict__ w2,
    const float* __restrict__ b2p,
    float* __restrict__ out)
{
    const int tid = threadIdx.x;
    const int lane = tid & 63;
    const int wib = __builtin_amdgcn_readfirstlane(tid >> 6);  // wave in block (uniform)
    const int wid = blockIdx.x * 4 + wib;
    const int NW = gridDim.x * 4;
    const int NGRP = E_TOTAL / 4;   // 400000

    // per-lane w2 values for cp = lane*4 + jj (undo u_gemm3 column permute)
    float w2v[4];
#pragma unroll
    for (int jj = 0; jj < 4; ++jj) {
        const int cp = lane * 4 + jj;
        const int n = (cp & ~31) + ((cp & 1) << 4) + ((cp & 31) >> 1);
        w2v[jj] = w2[n];
    }
    const float b2 = *b2p;
    const int loff = lane * 4;   // short offset within a U row

    for (int g = wid; g < NGRP; g += NW) {
        const int e0 = g * 4;
        // broadcast index loads (all lanes same addr -> single segment)
        const int4 s4 = *(const int4*)(srcE + e0);
        const int4 d4 = *(const int4*)(dstE + e0);
        int sv[4], dv[4];
        sv[0] = __builtin_amdgcn_readfirstlane(s4.x);
        sv[1] = __builtin_amdgcn_readfirstlane(s4.y);
        sv[2] = __builtin_amdgcn_readfirstlane(s4.z);
        sv[3] = __builtin_amdgcn_readfirstlane(s4.w);
        dv[0] = __builtin_amdgcn_readfirstlane(d4.x);
        dv[1] = __builtin_amdgcn_readfirstlane(d4.y);
        dv[2] = __builtin_amdgcn_readfirstlane(d4.z);
        dv[3] = __builtin_amdgcn_readfirstlane(d4.w);

        // 8 row loads, 8B/lane each, all independent (SGPR base + shared voff)
        bf16x4 u[4], v[4];
#pragma unroll
        for (int k = 0; k < 4; ++k) {
            u[k] = *(const bf16x4*)(Us + (size_t)sv[k] * H + loff);
            v[k] = *(const bf16x4*)(Ud + (size_t)dv[k] * H + loff);
        }

        float r[4];
#pragma unroll
        for (int k = 0; k < 4; ++k) {
            float acc = 0.f;
#pragma unroll
            for (int jj = 0; jj < 4; ++jj) {
                float hv = bf2f((unsigned short)u[k][jj]) + bf2f((unsigned short)v[k][jj]);
                acc = fmaf(fmaxf(hv, 0.f), w2v[jj], acc);
            }
            // 6-level wave butterfly: every lane ends with the full sum
            acc += __shfl_xor(acc, 1);
            acc += __shfl_xor(acc, 2);
            acc += __shfl_xor(acc, 4);
            acc += __shfl_xor(acc, 8);
            acc += __shfl_xor(acc, 16);
            acc += __shfl_xor(acc, 32);
            r[k] = acc + b2;
        }
        if (lane == 0) {
            float4 res;
            res.x = r[0]; res.y = r[1]; res.z = r[2]; res.w = r[3];
            *(float4*)(out + e0) = res;
        }
    }
}

// ======================= R4 fallback (ws too small) ======================

#define TILE_M 32
#define NTILES (E_TOTAL / TILE_M)
#define GRID 2500

#if defined(__has_attribute)
#if __has_attribute(amdgpu_waves_per_eu)
#define LB __launch_bounds__(256) __attribute__((amdgpu_waves_per_eu(2, 2)))
#else
#define LB __launch_bounds__(256, 2)
#endif
#else
#define LB __launch_bounds__(256, 2)
#endif

__global__ LB void edge_mlp(
    const unsigned short* __restrict__ hbf,
    const int* __restrict__ srcE,
    const int* __restrict__ dstE,
    const unsigned short* __restrict__ w1bf,
    const float* __restrict__ b1,
    const float* __restrict__ w2,
    const float* __restrict__ b2p,
    float* __restrict__ out)
{
    __shared__ __align__(16) unsigned short X[2][TILE_M * K2];
    __shared__ float red[2][TILE_M][5];

    const int tid = threadIdx.x;
    const int wave = tid >> 6;
    const int lane = tid & 63;
    const int lane15 = lane & 15;
    const int quad = lane >> 4;

    bf16x8 B[8][4];
#pragma unroll
    for (int kit = 0; kit < 8; ++kit)
#pragma unroll
        for (int nt = 0; nt < 4; ++nt) {
            int n = wave * 64 + nt * 16 + lane15;
            int k = kit * 32 + quad * 8;
            B[kit][nt] = *(const bf16x8*)(w1bf + n * K2 + k);
        }

    float b1v[4], w2v[4];
#pragma unroll
    for (int nt = 0; nt < 4; ++nt) {
        int n = wave * 64 + nt * 16 + lane15;
        b1v[nt] = b1[n];
        w2v[nt] = w2[n];
    }
    const float b2 = *b2p;

    const int r_off = tid >> 5;
    const int c = (tid & 31) ^ (r_off & 7);
    const int half = c >> 4;
    const int fc = c & 15;
    const int* idx_base = half ? dstE : srcE;
    const int gshort = fc * 8;

    const int t0 = blockIdx.x;
    int inode[4];

#pragma unroll
    for (int it = 0; it < 4; ++it)
        inode[it] = idx_base[t0 * TILE_M + it * 8 + r_off];
#pragma unroll
    for (int it = 0; it < 4; ++it)
        __builtin_amdgcn_global_load_lds(
            (gas_t)(hbf + inode[it] * D + gshort),
            (las_t)(&X[0][0] + it * 2048 + wave * 512), 16, 0, 0);
    {
        const int t1 = t0 + GRID;
#pragma unroll
        for (int it = 0; it < 4; ++it)
            inode[it] = idx_base[t1 * TILE_M + it * 8 + r_off];
    }

    int buf = 0;
    int prev_eb = -1;

    for (int tile = t0; tile < NTILES; tile += GRID) {
        __syncthreads();

        const int nt1 = tile + GRID;
        if (nt1 < NTILES) {
            unsigned short* Xn = &X[buf ^ 1][0];
#pragma unroll
            for (int it = 0; it < 4; ++it)
                __builtin_amdgcn_global_load_lds(
                    (gas_t)(hbf + inode[it] * D + gshort),
                    (las_t)(Xn + it * 2048 + wave * 512), 16, 0, 0);
        }
        const int nt2 = tile + 2 * GRID;
        if (nt2 < NTILES) {
            const int eb2 = nt2 * TILE_M;
#pragma unroll
            for (int it = 0; it < 4; ++it)
                inode[it] = idx_base[eb2 + it * 8 + r_off];
        }
        if (prev_eb >= 0 && tid < TILE_M) {
            float s = b2;
#pragma unroll
            for (int w = 0; w < 4; ++w) s += red[buf ^ 1][tid][w];
            out[prev_eb + tid] = s;
        }

        const unsigned short* Xc = &X[buf][0];
        f32x4 acc[2][4];
        const f32x4 zero = {0.f, 0.f, 0.f, 0.f};
#pragma unroll
        for (int ms = 0; ms < 2; ++ms)
#pragma unroll
            for (int nt = 0; nt < 4; ++nt)
                acc[ms][nt] = zero;

#pragma unroll
        for (int kit = 0; kit < 8; ++kit) {
            const int p8 = (((kit * 4 + quad) ^ (lane15 & 7))) * 8;
            bf16x8 a[2];
#pragma unroll
            for (int ms = 0; ms < 2; ++ms)
                a[ms] = *(const bf16x8*)&Xc[(ms * 16 + lane15) * K2 + p8];
#pragma unroll
            for (int ms = 0; ms < 2; ++ms)
#pragma unroll
                for (int nt = 0; nt < 4; ++nt)
                    acc[ms][nt] = __builtin_amdgcn_mfma_f32_16x16x32_bf16(
                        a[ms], B[kit][nt], acc[ms][nt], 0, 0, 0);
        }

#pragma unroll
        for (int ms = 0; ms < 2; ++ms)
#pragma unroll
            for (int r = 0; r < 4; ++r) {
                float p = 0.f;
#pragma unroll
                for (int nt = 0; nt < 4; ++nt) {
                    float hv = acc[ms][nt][r] + b1v[nt];
                    p = fmaf(fmaxf(hv, 0.f), w2v[nt], p);
                }
                p += __shfl_xor(p, 1, 16);
                p += __shfl_xor(p, 2, 16);
                p += __shfl_xor(p, 4, 16);
                p += __shfl_xor(p, 8, 16);
                if (lane15 == 0) red[buf][ms * 16 + quad * 4 + r][wave] = p;
            }
        prev_eb = tile * TILE_M;
        buf ^= 1;
    }

    __syncthreads();
    if (prev_eb >= 0 && tid < TILE_M) {
        float s = b2;
#pragma unroll
        for (int w = 0; w < 4; ++w) s += red[buf ^ 1][tid][w];
        out[prev_eb + tid] = s;
    }
}

// ================================ launch ================================

extern "C" void kernel_launch(void* const* d_in, const int* in_sizes, int n_in,
                              void* d_out, int out_size, void* d_ws, size_t ws_size,
                              hipStream_t stream) {
    const float* h    = (const float*)d_in[0];
    const int*   srcE = (const int*)d_in[1];
    const int*   dstE = (const int*)d_in[2];
    const float* W1   = (const float*)d_in[3];
    const float* b1   = (const float*)d_in[4];
    const float* w2   = (const float*)d_in[5];
    const float* b2   = (const float*)d_in[6];
    float* out = (float*)d_out;

    char* ws = (char*)d_ws;
    const size_t offUs   = 0;                        // 51,200,000 B
    const size_t offUd   = 51200000;                 // 51,200,000 B
    const size_t offHbf  = 102400000;                // 25,600,000 B
    const size_t offW1bf = 128000000;                // 131,072 B
    const size_t need    = offW1bf + 131072;         // 128,131,072 B

    if (ws_size >= need) {
        unsigned short* Us   = (unsigned short*)(ws + offUs);
        unsigned short* Ud   = (unsigned short*)(ws + offUd);
        unsigned short* hbf  = (unsigned short*)(ws + offHbf);
        unsigned short* w1bf = (unsigned short*)(ws + offW1bf);

        int n4h = NNODES * D / 4, n4w = H * K2 / 4;
        cvt_kernel<<<(n4h + n4w + 255) / 256, 256, 0, stream>>>(h, W1, hbf, w1bf, n4h, n4w);
        u_gemm3<<<4 * ((NNODES + 63) / 64), 256, 0, stream>>>(hbf, w1bf, b1, Us, Ud);
        edge_score<<<4096, 256, 0, stream>>>(Us, Ud, srcE, dstE, w2, b2, out);
    } else {
        unsigned short* hbf  = (unsigned short*)d_ws;
        unsigned short* w1bf = hbf + (size_t)NNODES * D;
        int n4h = NNODES * D / 4, n4w = H * K2 / 4;
        cvt_kernel<<<(n4h + n4w + 255) / 256, 256, 0, stream>>>(h, W1, hbf, w1bf, n4h, n4w);
        edge_mlp<<<GRID, 256, 0, stream>>>(hbf, srcE, dstE, w1bf, b1, w2, b2, out);
    }
}

// Round 2
// 363.698 us; speedup vs baseline: 1.0003x; 1.0003x over previous
//
#include <hip/hip_runtime.h>

// LinkPredictor: score[e] = w2 . relu(W1 . concat(h[src[e]], h[dst[e]]) + b1) + b2
// N_NODES=100000, N_EDGES=1600000, D=128, HIDDEN=256
//
// R14: hidden-dim split edge pass (exact: relu-dot partitions over n).
//   R13 post-mortem: 24-VGPR full-wave kernel == 68-VGPR grouped kernel at
//   ~224 us -> edge pass is at a memory-system ceiling (~774 MB L2-fill at
//   ~3.5 TB/s), NOT latency/occupancy-bound. Lever = reduce miss traffic.
//   Split: pass 0 reads U row bytes [0,256) (hidden 0..127), pass 1 bytes
//   [256,512); per-pass working set 51.2 MB (vs 102.4) -> higher L2 hit rate.
//   Partial scores round-trip through out[] (f32, L2/L3-resident).
//   Predict: combined edge FETCH 774 -> ~600 MB, combined dur 224 -> ~170 us.

#define NNODES 100000
#define E_TOTAL 1600000
#define D 128
#define K2 256
#define H 256

typedef short bf16x8 __attribute__((ext_vector_type(8)));
typedef float f32x4 __attribute__((ext_vector_type(4)));
typedef const __attribute__((address_space(1))) unsigned short* gas_t;
typedef __attribute__((address_space(3))) unsigned short* las_t;

__device__ __forceinline__ unsigned short f2bf(float f) {
    unsigned u = __float_as_uint(f);
    u += 0x7fff + ((u >> 16) & 1);   // round-to-nearest-even
    return (unsigned short)(u >> 16);
}
__device__ __forceinline__ float bf2f(unsigned short s) {
    return __uint_as_float((unsigned)s << 16);
}

// ---------------- cvt: h and W1 -> bf16 ----------------
__global__ void cvt_kernel(const float* __restrict__ h, const float* __restrict__ w1,
                           unsigned short* __restrict__ hbf, unsigned short* __restrict__ w1bf,
                           int n4h, int n4w) {
    int i = blockIdx.x * blockDim.x + threadIdx.x;
    const float* s; unsigned short* d; int j;
    if (i < n4h) { s = h; d = hbf; j = i; }
    else if (i < n4h + n4w) { s = w1; d = w1bf; j = i - n4h; }
    else return;
    float4 v = ((const float4*)s)[j];
    ushort4 o;
    o.x = f2bf(v.x); o.y = f2bf(v.y); o.z = f2bf(v.z); o.w = f2bf(v.w);
    ((ushort4*)d)[j] = o;
}

// ---------------- u_gemm v3: N-split, direct C-layout stores ----------------
// blockIdx bx: tile = bx>>2 (64 node rows), half = (bx>>1)&1 (0: Us + b1 fold,
// 1: Ud), nh = bx&1 (cols 0-127 vs 128-255 of the half's output).
// Wave w owns true cols n = nh*128 + w*32 + nt*16 + l15, nt in {0,1}.
// Store: row m, lane l15 packs (nt0,nt1) -> dword at short-offset
// nh*128 + w*32 + l15*2  (c' = that + nt).
__global__ __launch_bounds__(256, 4) void u_gemm3(
    const unsigned short* __restrict__ hbf,
    const unsigned short* __restrict__ w1bf,
    const float* __restrict__ b1,
    unsigned short* __restrict__ Us,
    unsigned short* __restrict__ Ud)
{
    __shared__ __align__(16) unsigned short A[64 * 128];   // 16384 B

    const int tid = threadIdx.x;
    const int wave = tid >> 6;
    const int lane = tid & 63;
    const int l15 = lane & 15;
    const int quad = lane >> 4;

    const int tile = blockIdx.x >> 2;
    const int half = (blockIdx.x >> 1) & 1;
    const int nh = blockIdx.x & 1;
    const int r0 = tile * 64;
    int rows = NNODES - r0; if (rows > 64) rows = 64;
    const int koff = half * 128;
    unsigned short* U = half ? Ud : Us;

    // --- issue async stage of A (16 KB), XOR swizzle c = p ^ (r&15) ---
#pragma unroll
    for (int it = 0; it < 4; ++it) {
        const int s = it * 256 + tid;      // 16B slot 0..1023
        const int r = s >> 4;              // row 0..63
        const int p = s & 15;              // position chunk
        const int c = p ^ (r & 15);        // content chunk
        if (r < rows)
            __builtin_amdgcn_global_load_lds(
                (gas_t)(hbf + (size_t)(r0 + r) * D + c * 8),
                (las_t)(A + it * 2048 + wave * 512), 16, 0, 0);
    }

    // --- B fragments + bias while DMA is in flight ---
    bf16x8 B[4][2];
    float bias[2];
#pragma unroll
    for (int nt = 0; nt < 2; ++nt) {
        const int n = nh * 128 + wave * 32 + nt * 16 + l15;
        bias[nt] = half ? 0.f : b1[n];
#pragma unroll
        for (int kit = 0; kit < 4; ++kit)
            B[kit][nt] = *(const bf16x8*)(w1bf + (size_t)n * K2 + koff + kit * 32 + quad * 8);
    }

    __syncthreads();   // vmcnt(0): A landed

    f32x4 acc[4][2];
    const f32x4 zero = {0.f, 0.f, 0.f, 0.f};
#pragma unroll
    for (int ms = 0; ms < 4; ++ms)
#pragma unroll
        for (int nt = 0; nt < 2; ++nt)
            acc[ms][nt] = zero;

#pragma unroll
    for (int kit = 0; kit < 4; ++kit) {
        bf16x8 a[4];
#pragma unroll
        for (int ms = 0; ms < 4; ++ms) {
            const int row = ms * 16 + l15;
            const int p = (kit * 4 + quad) ^ l15;
            a[ms] = *(const bf16x8*)&A[row * 128 + p * 8];
        }
#pragma unroll
        for (int ms = 0; ms < 4; ++ms)
#pragma unroll
            for (int nt = 0; nt < 2; ++nt)
                acc[ms][nt] = __builtin_amdgcn_mfma_f32_16x16x32_bf16(
                    a[ms], B[kit][nt], acc[ms][nt], 0, 0, 0);
    }

    // --- direct permuted store: dword per (ms,r), 64B segment per quad ---
    const int coff = nh * 128 + wave * 32 + l15 * 2;   // short offset in U row
#pragma unroll
    for (int ms = 0; ms < 4; ++ms) {
#pragma unroll
        for (int r = 0; r < 4; ++r) {
            const int m = ms * 16 + quad * 4 + r;
            if (m < rows) {
                const unsigned lo = f2bf(acc[ms][0][r] + bias[0]);
                const unsigned hi = f2bf(acc[ms][1][r] + bias[1]);
                *(unsigned*)(U + (size_t)(r0 + m) * H + coff) = lo | (hi << 16);
            }
        }
    }
}

// ---------------- edge pass (R14: hidden-dim half split) ----------------
// U' layout: within each 32-col block, c'' = l15*2+nt holds n'' = nt*16+l15.
// Pass `half` reads shorts cp in [half*128, half*128+128) of each U row
// (contiguous 256 B). 16-lane group handles 4 edges; lane l reads 8 shorts
// at cp = half*128 + l*8. w2v[j] = w2[perm(cp+j)].
// Pass 0: out[e] = partial0 + b2.  Pass 1: out[e] += partial1.
__global__ __launch_bounds__(256) void edge_score_half(
    const unsigned short* __restrict__ Us,
    const unsigned short* __restrict__ Ud,
    const int* __restrict__ srcE,
    const int* __restrict__ dstE,
    const float* __restrict__ w2,
    const float* __restrict__ b2p,
    float* __restrict__ out,
    int half)
{
    const int gt = blockIdx.x * 256 + threadIdx.x;
    const int l = gt & 15;
    const int q = gt >> 4;
    const int Q = (gridDim.x * 256) >> 4;
    const int NGRP = E_TOTAL / 4;   // 400000

    // per-lane w2 values for cp = half*128 + l*8 + j (undo u_gemm3 col permute)
    float w2v[8];
#pragma unroll
    for (int j = 0; j < 8; ++j) {
        const int cp = half * 128 + l * 8 + j;
        const int n = (cp & ~31) + ((cp & 1) << 4) + ((cp & 31) >> 1);
        w2v[j] = w2[n];
    }
    const float b2 = *b2p;
    const int loff = half * 128 + l * 8;   // short offset within a U row

    for (int g = q; g < NGRP; g += Q) {
        const int e0 = g * 4;
        const int4 s4 = *(const int4*)(srcE + e0);
        const int4 d4 = *(const int4*)(dstE + e0);
        const int sv[4] = {s4.x, s4.y, s4.z, s4.w};
        const int dv[4] = {d4.x, d4.y, d4.z, d4.w};

        bf16x8 u[4], v[4];
#pragma unroll
        for (int k = 0; k < 4; ++k) {
            u[k] = *(const bf16x8*)(Us + (size_t)sv[k] * H + loff);
            v[k] = *(const bf16x8*)(Ud + (size_t)dv[k] * H + loff);
        }

        float4 prev;
        if (half) prev = *(const float4*)(out + e0);   // partial from pass 0

        float4 res;
        float* resp = (float*)&res;
        const float* prevp = (const float*)&prev;
#pragma unroll
        for (int k = 0; k < 4; ++k) {
            float acc = 0.f;
#pragma unroll
            for (int j = 0; j < 8; ++j) {
                float hv = bf2f((unsigned short)u[k][j]) + bf2f((unsigned short)v[k][j]);
                acc = fmaf(fmaxf(hv, 0.f), w2v[j], acc);
            }
            acc += __shfl_xor(acc, 1, 16);
            acc += __shfl_xor(acc, 2, 16);
            acc += __shfl_xor(acc, 4, 16);
            acc += __shfl_xor(acc, 8, 16);
            resp[k] = acc + (half ? prevp[k] : b2);
        }
        if (l == 0) *(float4*)(out + e0) = res;
    }
}

// ======================= R4 fallback (ws too small) ======================

#define TILE_M 32
#define NTILES (E_TOTAL / TILE_M)
#define GRID 2500

#if defined(__has_attribute)
#if __has_attribute(amdgpu_waves_per_eu)
#define LB __launch_bounds__(256) __attribute__((amdgpu_waves_per_eu(2, 2)))
#else
#define LB __launch_bounds__(256, 2)
#endif
#else
#define LB __launch_bounds__(256, 2)
#endif

__global__ LB void edge_mlp(
    const unsigned short* __restrict__ hbf,
    const int* __restrict__ srcE,
    const int* __restrict__ dstE,
    const unsigned short* __restrict__ w1bf,
    const float* __restrict__ b1,
    const float* __restrict__ w2,
    const float* __restrict__ b2p,
    float* __restrict__ out)
{
    __shared__ __align__(16) unsigned short X[2][TILE_M * K2];
    __shared__ float red[2][TILE_M][5];

    const int tid = threadIdx.x;
    const int wave = tid >> 6;
    const int lane = tid & 63;
    const int lane15 = lane & 15;
    const int quad = lane >> 4;

    bf16x8 B[8][4];
#pragma unroll
    for (int kit = 0; kit < 8; ++kit)
#pragma unroll
        for (int nt = 0; nt < 4; ++nt) {
            int n = wave * 64 + nt * 16 + lane15;
            int k = kit * 32 + quad * 8;
            B[kit][nt] = *(const bf16x8*)(w1bf + n * K2 + k);
        }

    float b1v[4], w2v[4];
#pragma unroll
    for (int nt = 0; nt < 4; ++nt) {
        int n = wave * 64 + nt * 16 + lane15;
        b1v[nt] = b1[n];
        w2v[nt] = w2[n];
    }
    const float b2 = *b2p;

    const int r_off = tid >> 5;
    const int c = (tid & 31) ^ (r_off & 7);
    const int half = c >> 4;
    const int fc = c & 15;
    const int* idx_base = half ? dstE : srcE;
    const int gshort = fc * 8;

    const int t0 = blockIdx.x;
    int inode[4];

#pragma unroll
    for (int it = 0; it < 4; ++it)
        inode[it] = idx_base[t0 * TILE_M + it * 8 + r_off];
#pragma unroll
    for (int it = 0; it < 4; ++it)
        __builtin_amdgcn_global_load_lds(
            (gas_t)(hbf + inode[it] * D + gshort),
            (las_t)(&X[0][0] + it * 2048 + wave * 512), 16, 0, 0);
    {
        const int t1 = t0 + GRID;
#pragma unroll
        for (int it = 0; it < 4; ++it)
            inode[it] = idx_base[t1 * TILE_M + it * 8 + r_off];
    }

    int buf = 0;
    int prev_eb = -1;

    for (int tile = t0; tile < NTILES; tile += GRID) {
        __syncthreads();

        const int nt1 = tile + GRID;
        if (nt1 < NTILES) {
            unsigned short* Xn = &X[buf ^ 1][0];
#pragma unroll
            for (int it = 0; it < 4; ++it)
                __builtin_amdgcn_global_load_lds(
                    (gas_t)(hbf + inode[it] * D + gshort),
                    (las_t)(Xn + it * 2048 + wave * 512), 16, 0, 0);
        }
        const int nt2 = tile + 2 * GRID;
        if (nt2 < NTILES) {
            const int eb2 = nt2 * TILE_M;
#pragma unroll
            for (int it = 0; it < 4; ++it)
                inode[it] = idx_base[eb2 + it * 8 + r_off];
        }
        if (prev_eb >= 0 && tid < TILE_M) {
            float s = b2;
#pragma unroll
            for (int w = 0; w < 4; ++w) s += red[buf ^ 1][tid][w];
            out[prev_eb + tid] = s;
        }

        const unsigned short* Xc = &X[buf][0];
        f32x4 acc[2][4];
        const f32x4 zero = {0.f, 0.f, 0.f, 0.f};
#pragma unroll
        for (int ms = 0; ms < 2; ++ms)
#pragma unroll
            for (int nt = 0; nt < 4; ++nt)
                acc[ms][nt] = zero;

#pragma unroll
        for (int kit = 0; kit < 8; ++kit) {
            const int p8 = (((kit * 4 + quad) ^ (lane15 & 7))) * 8;
            bf16x8 a[2];
#pragma unroll
            for (int ms = 0; ms < 2; ++ms)
                a[ms] = *(const bf16x8*)&Xc[(ms * 16 + lane15) * K2 + p8];
#pragma unroll
            for (int ms = 0; ms < 2; ++ms)
#pragma unroll
                for (int nt = 0; nt < 4; ++nt)
                    acc[ms][nt] = __builtin_amdgcn_mfma_f32_16x16x32_bf16(
                        a[ms], B[kit][nt], acc[ms][nt], 0, 0, 0);
        }

#pragma unroll
        for (int ms = 0; ms < 2; ++ms)
#pragma unroll
            for (int r = 0; r < 4; ++r) {
                float p = 0.f;
#pragma unroll
                for (int nt = 0; nt < 4; ++nt) {
                    float hv = acc[ms][nt][r] + b1v[nt];
                    p = fmaf(fmaxf(hv, 0.f), w2v[nt], p);
                }
                p += __shfl_xor(p, 1, 16);
                p += __shfl_xor(p, 2, 16);
                p += __shfl_xor(p, 4, 16);
                p += __shfl_xor(p, 8, 16);
                if (lane15 == 0) red[buf][ms * 16 + quad * 4 + r][wave] = p;
            }
        prev_eb = tile * TILE_M;
        buf ^= 1;
    }

    __syncthreads();
    if (prev_eb >= 0 && tid < TILE_M) {
        float s = b2;
#pragma unroll
        for (int w = 0; w < 4; ++w) s += red[buf ^ 1][tid][w];
        out[prev_eb + tid] = s;
    }
}

// ================================ launch ================================

extern "C" void kernel_launch(void* const* d_in, const int* in_sizes, int n_in,
                              void* d_out, int out_size, void* d_ws, size_t ws_size,
                              hipStream_t stream) {
    const float* h    = (const float*)d_in[0];
    const int*   srcE = (const int*)d_in[1];
    const int*   dstE = (const int*)d_in[2];
    const float* W1   = (const float*)d_in[3];
    const float* b1   = (const float*)d_in[4];
    const float* w2   = (const float*)d_in[5];
    const float* b2   = (const float*)d_in[6];
    float* out = (float*)d_out;

    char* ws = (char*)d_ws;
    const size_t offUs   = 0;                        // 51,200,000 B
    const size_t offUd   = 51200000;                 // 51,200,000 B
    const size_t offHbf  = 102400000;                // 25,600,000 B
    const size_t offW1bf = 128000000;                // 131,072 B
    const size_t need    = offW1bf + 131072;         // 128,131,072 B

    if (ws_size >= need) {
        unsigned short* Us   = (unsigned short*)(ws + offUs);
        unsigned short* Ud   = (unsigned short*)(ws + offUd);
        unsigned short* hbf  = (unsigned short*)(ws + offHbf);
        unsigned short* w1bf = (unsigned short*)(ws + offW1bf);

        int n4h = NNODES * D / 4, n4w = H * K2 / 4;
        cvt_kernel<<<(n4h + n4w + 255) / 256, 256, 0, stream>>>(h, W1, hbf, w1bf, n4h, n4w);
        u_gemm3<<<4 * ((NNODES + 63) / 64), 256, 0, stream>>>(hbf, w1bf, b1, Us, Ud);
        edge_score_half<<<4096, 256, 0, stream>>>(Us, Ud, srcE, dstE, w2, b2, out, 0);
        edge_score_half<<<4096, 256, 0, stream>>>(Us, Ud, srcE, dstE, w2, b2, out, 1);
    } else {
        unsigned short* hbf  = (unsigned short*)d_ws;
        unsigned short* w1bf = hbf + (size_t)NNODES * D;
        int n4h = NNODES * D / 4, n4w = H * K2 / 4;
        cvt_kernel<<<(n4h + n4w + 255) / 256, 256, 0, stream>>>(h, W1, hbf, w1bf, n4h, n4w);
        edge_mlp<<<GRID, 256, 0, stream>>>(hbf, srcE, dstE, w1bf, b1, w2, b2, out);
    }
}